// Round 2
// baseline (1012.456 us; speedup 1.0000x reference)
//
#include <hip/hip_runtime.h>

#define NTOK 4096
#define NEXP 8
#define HD 2048
#define ID 1408

typedef unsigned short u16;
typedef __attribute__((ext_vector_type(8))) short short8;
typedef __attribute__((ext_vector_type(4))) unsigned short ushort4v;
typedef __attribute__((ext_vector_type(4))) float f32x4;

__device__ __forceinline__ u16 f2bf(float f) {
  unsigned int u = __float_as_uint(f);
  u += 0x7FFFu + ((u >> 16) & 1u);   // RNE
  return (u16)(u >> 16);
}
__device__ __forceinline__ float bf2f(u16 b) {
  return __uint_as_float(((unsigned int)b) << 16);
}

// fp32 -> bf16 bulk convert, 8 elems/thread
__global__ void cvt_kernel(const float* __restrict__ s, u16* __restrict__ d, long n8) {
  long i = (long)blockIdx.x * blockDim.x + threadIdx.x;
  if (i >= n8) return;
  const float4* s4 = (const float4*)s;
  float4 a = s4[2*i], b = s4[2*i+1];
  short8 o;
  o[0] = (short)f2bf(a.x); o[1] = (short)f2bf(a.y);
  o[2] = (short)f2bf(a.z); o[3] = (short)f2bf(a.w);
  o[4] = (short)f2bf(b.x); o[5] = (short)f2bf(b.y);
  o[6] = (short)f2bf(b.z); o[7] = (short)f2bf(b.w);
  *(short8*)(d + 8*i) = o;
}

// router: logits (fp32), softmax, top-2, per-expert scatter lists (rank packed
// in bit 16 of ptok entry), plus fused x fp32->bf16 conversion.
__global__ void router_kernel(const float* __restrict__ x, const float* __restrict__ gw,
                              u16* __restrict__ xb,
                              float* __restrict__ logits, int* __restrict__ cnt,
                              int* __restrict__ ptok, float* __restrict__ pw) {
  int t = blockIdx.x * 4 + (threadIdx.x >> 6);   // one wave per token
  int lane = threadIdx.x & 63;
  if (t >= NTOK) return;
  const float4* xr = (const float4*)(x + (size_t)t * HD);
  float dot[NEXP];
#pragma unroll
  for (int e = 0; e < NEXP; ++e) dot[e] = 0.f;
#pragma unroll
  for (int c = 0; c < 8; ++c) {                  // 2048/4/64 = 8 chunks
    float4 xv = xr[c*64 + lane];
    ushort4v o;
    o[0] = f2bf(xv.x); o[1] = f2bf(xv.y); o[2] = f2bf(xv.z); o[3] = f2bf(xv.w);
    *(ushort4v*)(xb + (size_t)t*HD + (c*64 + lane)*4) = o;
#pragma unroll
    for (int e = 0; e < NEXP; ++e) {
      float4 gv = ((const float4*)(gw + e*HD))[c*64 + lane];
      dot[e] += xv.x*gv.x + xv.y*gv.y + xv.z*gv.z + xv.w*gv.w;
    }
  }
#pragma unroll
  for (int off = 32; off > 0; off >>= 1) {
#pragma unroll
    for (int e = 0; e < NEXP; ++e) dot[e] += __shfl_xor(dot[e], off);
  }
  if (lane < NEXP) logits[(size_t)t*NEXP + lane] = dot[lane];
  if (lane == 0) {
    float mx = dot[0];
#pragma unroll
    for (int e = 1; e < NEXP; ++e) mx = fmaxf(mx, dot[e]);
    float p[NEXP];
#pragma unroll
    for (int e = 0; e < NEXP; ++e) p[e] = __expf(dot[e] - mx);
    int e0 = 0;
#pragma unroll
    for (int e = 1; e < NEXP; ++e) if (p[e] > p[e0]) e0 = e;   // ties -> lowest idx
    int e1 = (e0 == 0) ? 1 : 0;
#pragma unroll
    for (int e = 0; e < NEXP; ++e) if (e != e0 && p[e] > p[e1]) e1 = e;
    float denom = p[e0] + p[e1];
    int pos0 = atomicAdd(&cnt[e0], 1);
    ptok[e0*NTOK + pos0] = t;              // rank 0
    pw[e0*NTOK + pos0] = p[e0] / denom;
    int pos1 = atomicAdd(&cnt[e1], 1);
    ptok[e1*NTOK + pos1] = t | 0x10000;    // rank 1
    pw[e1*NTOK + pos1] = p[e1] / denom;
  }
}

__global__ void prefix_kernel(const int* __restrict__ cnt, int* __restrict__ offs) {
  if (threadIdx.x == 0) {
    int a = 0;
    for (int e = 0; e < NEXP; ++e) { offs[e] = a; a += cnt[e]; }
  }
}

// GEMM1: LDS-free. Fragments loaded straight from global in MFMA operand
// layout: lane needs row (l&15), 8 contiguous k at (l>>4)*8 -> one dwordx4.
// h = silu(x@wg^T) * (x@wu^T), rows gathered via ptok, stored bf16.
__global__ __launch_bounds__(256, 2) void gemm1_kernel(
    const u16* __restrict__ xb, const u16* __restrict__ wgb, const u16* __restrict__ wub,
    const int* __restrict__ cnt, const int* __restrict__ offs,
    const int* __restrict__ ptok, u16* __restrict__ hbuf) {
  int e = blockIdx.z, mt = blockIdx.y, nt = blockIdx.x;
  int c = cnt[e];
  if (mt * 128 >= c) return;
  int off = offs[e];

  int tid = threadIdx.x;
  int lane = tid & 63, wv = tid >> 6, wr = wv >> 1, wc = wv & 1;
  int fm = lane & 15, kg = lane >> 4;

  const u16* aptr[4];
#pragma unroll
  for (int i = 0; i < 4; ++i) {
    int m = mt*128 + wr*64 + i*16 + fm;
    int mm = m < c ? m : c - 1;
    int tok = ptok[e*NTOK + mm] & 0xFFFF;
    aptr[i] = xb + (size_t)tok*HD + kg*8;
  }
  const u16* gptr[4];
  const u16* uptr[4];
#pragma unroll
  for (int j = 0; j < 4; ++j) {
    int n = nt*128 + wc*64 + j*16 + fm;
    gptr[j] = wgb + ((size_t)e*ID + n)*HD + kg*8;
    uptr[j] = wub + ((size_t)e*ID + n)*HD + kg*8;
  }

  f32x4 accg[4][4], accu[4][4];
#pragma unroll
  for (int i = 0; i < 4; ++i)
#pragma unroll
    for (int j = 0; j < 4; ++j) {
      accg[i][j] = {0.f, 0.f, 0.f, 0.f};
      accu[i][j] = {0.f, 0.f, 0.f, 0.f};
    }

  for (int k0 = 0; k0 < HD; k0 += 32) {
    short8 af[4], bg[4], bu[4];
#pragma unroll
    for (int i = 0; i < 4; ++i) af[i] = *(const short8*)(aptr[i] + k0);
#pragma unroll
    for (int j = 0; j < 4; ++j) {
      bg[j] = *(const short8*)(gptr[j] + k0);
      bu[j] = *(const short8*)(uptr[j] + k0);
    }
#pragma unroll
    for (int i = 0; i < 4; ++i)
#pragma unroll
      for (int j = 0; j < 4; ++j) {
        accg[i][j] = __builtin_amdgcn_mfma_f32_16x16x32_bf16(af[i], bg[j], accg[i][j], 0, 0, 0);
        accu[i][j] = __builtin_amdgcn_mfma_f32_16x16x32_bf16(af[i], bu[j], accu[i][j], 0, 0, 0);
      }
  }

#pragma unroll
  for (int i = 0; i < 4; ++i) {
#pragma unroll
    for (int r = 0; r < 4; ++r) {
      int slot = mt*128 + wr*64 + i*16 + kg*4 + r;
      if (slot < c) {
        size_t rowb = (size_t)(off + slot) * ID + nt*128 + wc*64 + fm;
#pragma unroll
        for (int j = 0; j < 4; ++j) {
          float g = accg[i][j][r], u = accu[i][j][r];
          float hh = g * u / (1.f + __expf(-g));   // silu(g)*u
          hbuf[rowb + (size_t)j*16] = f2bf(hh);
        }
      }
    }
  }
}

// GEMM2: LDS-free. y = h @ wd^T, weighted, written bf16 to token-major
// ybuf[tok*2+rank] -- no atomics.
__global__ __launch_bounds__(256, 2) void gemm2_kernel(
    const u16* __restrict__ hbuf, const u16* __restrict__ wdb,
    const int* __restrict__ cnt, const int* __restrict__ offs,
    const int* __restrict__ ptok, const float* __restrict__ pw,
    u16* __restrict__ ybuf) {
  int e = blockIdx.z, mt = blockIdx.y, nt = blockIdx.x;
  int c = cnt[e];
  if (mt * 128 >= c) return;
  int off = offs[e];

  int tid = threadIdx.x;
  int lane = tid & 63, wv = tid >> 6, wr = wv >> 1, wc = wv & 1;
  int fm = lane & 15, kg = lane >> 4;

  const u16* aptr[4];
#pragma unroll
  for (int i = 0; i < 4; ++i) {
    int m = mt*128 + wr*64 + i*16 + fm;
    int mm = m < c ? m : c - 1;
    aptr[i] = hbuf + (size_t)(off + mm)*ID + kg*8;
  }
  const u16* bptr[4];
#pragma unroll
  for (int j = 0; j < 4; ++j) {
    int n = nt*128 + wc*64 + j*16 + fm;
    bptr[j] = wdb + ((size_t)e*HD + n)*ID + kg*8;
  }

  f32x4 acc[4][4];
#pragma unroll
  for (int i = 0; i < 4; ++i)
#pragma unroll
    for (int j = 0; j < 4; ++j) acc[i][j] = {0.f, 0.f, 0.f, 0.f};

#pragma unroll 2
  for (int k0 = 0; k0 < ID; k0 += 32) {
    short8 af[4], bf[4];
#pragma unroll
    for (int i = 0; i < 4; ++i) af[i] = *(const short8*)(aptr[i] + k0);
#pragma unroll
    for (int j = 0; j < 4; ++j) bf[j] = *(const short8*)(bptr[j] + k0);
#pragma unroll
    for (int i = 0; i < 4; ++i)
#pragma unroll
      for (int j = 0; j < 4; ++j)
        acc[i][j] = __builtin_amdgcn_mfma_f32_16x16x32_bf16(af[i], bf[j], acc[i][j], 0, 0, 0);
  }

#pragma unroll
  for (int i = 0; i < 4; ++i) {
#pragma unroll
    for (int r = 0; r < 4; ++r) {
      int slot = mt*128 + wr*64 + i*16 + kg*4 + r;
      if (slot < c) {
        int entry = ptok[e*NTOK + slot];
        int tok = entry & 0xFFFF;
        int rank = entry >> 16;
        float wgt = pw[e*NTOK + slot];
        u16* orow = ybuf + ((size_t)tok*2 + rank)*HD + nt*128 + wc*64 + fm;
#pragma unroll
        for (int j = 0; j < 4; ++j)
          orow[j*16] = f2bf(wgt * acc[i][j][r]);
      }
    }
  }
}

// combine: out[t] = ybuf[2t] + ybuf[2t+1]  (bf16 -> fp32)
__global__ void combine_kernel(const u16* __restrict__ ybuf, float* __restrict__ out) {
  int t = blockIdx.x;
  int col = threadIdx.x * 8;
  short8 a = *(const short8*)(ybuf + ((size_t)t*2)*HD + col);
  short8 b = *(const short8*)(ybuf + ((size_t)t*2 + 1)*HD + col);
  float4 o0, o1;
  o0.x = bf2f((u16)a[0]) + bf2f((u16)b[0]);
  o0.y = bf2f((u16)a[1]) + bf2f((u16)b[1]);
  o0.z = bf2f((u16)a[2]) + bf2f((u16)b[2]);
  o0.w = bf2f((u16)a[3]) + bf2f((u16)b[3]);
  o1.x = bf2f((u16)a[4]) + bf2f((u16)b[4]);
  o1.y = bf2f((u16)a[5]) + bf2f((u16)b[5]);
  o1.z = bf2f((u16)a[6]) + bf2f((u16)b[6]);
  o1.w = bf2f((u16)a[7]) + bf2f((u16)b[7]);
  float4* dst = (float4*)(out + (size_t)t*HD + col);
  dst[0] = o0;
  dst[1] = o1;
}

extern "C" void kernel_launch(void* const* d_in, const int* in_sizes, int n_in,
                              void* d_out, int out_size, void* d_ws, size_t ws_size,
                              hipStream_t stream) {
  const float* x  = (const float*)d_in[0];
  const float* gw = (const float*)d_in[1];
  const float* wg = (const float*)d_in[2];
  const float* wu = (const float*)d_in[3];
  const float* wd = (const float*)d_in[4];
  float* out = (float*)d_out;

  // workspace carve (bytes), all 16B-aligned.
  // ybuf (33.5 MB, written by gemm2) overlaps xb+wgb head (dead by then).
  char* p = (char*)d_ws;
  u16*   ybuf = (u16*)(p);                    //  33,554,432 B : y bf16 [8192,2048] (aliases xb/wgb)
  u16*   xb   = (u16*)(p);                    //  16,777,216 B : x bf16 [4096,2048]
  u16*   wgb  = (u16*)(p + 16777216UL);       //  46,137,344 B : wg bf16
  u16*   wub  = (u16*)(p + 62914560UL);       //  46,137,344 B : wu bf16
  u16*   wdb  = (u16*)(p + 109051904UL);      //  46,137,344 B : wd bf16
  u16*   hbuf = (u16*)(p + 155189248UL);      //  23,068,672 B : h bf16 [8192,1408]
  int*   ptok = (int*)(p + 178257920UL);      //     131,072 B (tok | rank<<16)
  float* pww  = (float*)(p + 178388992UL);    //     131,072 B
  int*   cnt  = (int*)(p + 178520064UL);      //         256 B
  int*   offs = (int*)(p + 178520320UL);      //         256 B

  hipMemsetAsync(cnt, 0, NEXP * sizeof(int), stream);

  cvt_kernel<<<11264, 256, 0, stream>>>(wg, wgb, (long)NEXP * ID * HD / 8);
  cvt_kernel<<<11264, 256, 0, stream>>>(wu, wub, (long)NEXP * ID * HD / 8);
  cvt_kernel<<<11264, 256, 0, stream>>>(wd, wdb, (long)NEXP * HD * ID / 8);

  router_kernel<<<1024, 256, 0, stream>>>(x, gw, xb, out + (size_t)NTOK * HD, cnt, ptok, pww);
  prefix_kernel<<<1, 64, 0, stream>>>(cnt, offs);

  gemm1_kernel<<<dim3(11, 32, 8), 256, 0, stream>>>(xb, wgb, wub, cnt, offs, ptok, hbuf);
  gemm2_kernel<<<dim3(16, 32, 8), 256, 0, stream>>>(hbuf, wdb, cnt, offs, ptok, pww, ybuf);
  combine_kernel<<<NTOK, 256, 0, stream>>>(ybuf, out);
}